// Round 4
// baseline (324.944 us; speedup 1.0000x reference)
//
#include <hip/hip_runtime.h>
#include <hip/hip_bf16.h>
#include <stdint.h>

#define N_TOTAL 40000
#define NROW    20000
#define D       512
#define NSAMP   25
#define KDIM    1024   // 2*D
#define BM      128
#define BN      128
#define BK      64

typedef __bf16 bf16x8 __attribute__((ext_vector_type(8)));
typedef float  f32x4  __attribute__((ext_vector_type(4)));

__device__ inline float bf2f(unsigned short u) {
  union { uint32_t u; float f; } cv; cv.u = ((uint32_t)u) << 16; return cv.f;
}
__device__ inline unsigned short f2bf(float f) {
  union { float f; uint32_t u; } cv; cv.f = f;
  uint32_t u = cv.u;
  uint32_t r = (u + 0x7fffu + ((u >> 16) & 1u)) >> 16;  // RNE
  return (unsigned short)r;
}

__device__ inline void gload_lds16(const void* gsrc, void* ldst) {
  __builtin_amdgcn_global_load_lds(
      (const __attribute__((address_space(1))) uint32_t*)gsrc,
      (__attribute__((address_space(3))) uint32_t*)ldst,
      16, 0, 0);
}

// K0: convert features (f32->bf16) and W (f32->bf16)
__global__ void convert_kernel(const float* __restrict__ feat,
                               const float* __restrict__ W,
                               unsigned short* __restrict__ fbf,
                               unsigned short* __restrict__ wbf) {
  const int NF = N_TOTAL * D;      // 20,480,000
  const int NW = D * KDIM;         // 524,288
  const int total4 = (NF + NW) >> 2;
  for (int i = blockIdx.x * blockDim.x + threadIdx.x; i < total4;
       i += gridDim.x * blockDim.x) {
    int e = i << 2;
    float4 v;
    unsigned short* dst;
    if (e < NF) { v = *(const float4*)(feat + e); dst = fbf + e; }
    else        { int e2 = e - NF; v = *(const float4*)(W + e2); dst = wbf + e2; }
    ushort4 o;
    o.x = f2bf(v.x); o.y = f2bf(v.y); o.z = f2bf(v.z); o.w = f2bf(v.w);
    *(ushort4*)dst = o;
  }
}

// K1: gather self row + mean of 25 neighbor rows -> hcat bf16 [NROW][1024]
__launch_bounds__(256, 3)
__global__ void gather_kernel(const unsigned short* __restrict__ fbf,
                              const int* __restrict__ self_idx,
                              const int* __restrict__ neigh_idx,
                              unsigned short* __restrict__ hcat) {
  const int wid = threadIdx.x >> 6;
  const int lane = threadIdx.x & 63;
  const int n = blockIdx.x * 4 + wid;
  if (n >= NROW) return;
  const int col8 = lane * 8;   // 8 bf16 per lane covers 512 cols

  int si = __builtin_amdgcn_readfirstlane(self_idx[n]);
  uint4 sv = *(const uint4*)(fbf + (long)si * D + col8);
  *(uint4*)(hcat + (long)n * KDIM + col8) = sv;

  int idx[NSAMP];
#pragma unroll
  for (int s = 0; s < NSAMP; ++s)
    idx[s] = __builtin_amdgcn_readfirstlane(neigh_idx[n * NSAMP + s]);

  uint4 v[NSAMP];
#pragma unroll
  for (int s = 0; s < NSAMP; ++s)
    v[s] = *(const uint4*)(fbf + (long)idx[s] * D + col8);

  float acc[8];
#pragma unroll
  for (int j = 0; j < 8; ++j) acc[j] = 0.f;
#pragma unroll
  for (int s = 0; s < NSAMP; ++s) {
    const unsigned short* u = (const unsigned short*)&v[s];
#pragma unroll
    for (int j = 0; j < 8; ++j) acc[j] += bf2f(u[j]);
  }
  unsigned short ob[8];
#pragma unroll
  for (int j = 0; j < 8; ++j) ob[j] = f2bf(acc[j] * (1.0f / NSAMP));
  *(uint4*)(hcat + (long)n * KDIM + D + col8) = *(uint4*)ob;
}

// K2: h = relu(hcat @ W^T + b), BM=128 x BN=128, BK=64, 4 waves, fused BN stats.
// LDS per matrix: [sub 0..7][row 0..127][8 bf16], sub = ks*4 + koff
__launch_bounds__(256)
__global__ void gemm_kernel(const unsigned short* __restrict__ hcat,
                            const unsigned short* __restrict__ wbf,
                            const float* __restrict__ bias,
                            float* __restrict__ h,
                            float* __restrict__ csum,
                            float* __restrict__ csq) {
  __shared__ unsigned short ldsA[8192];   // 16 KB: 128 rows x 64 k
  __shared__ unsigned short ldsB[8192];   // 16 KB
  const int tid = threadIdx.x;
  const int lane = tid & 63, wid = tid >> 6;
  const int mb = blockIdx.x, nb = blockIdx.y;
  const int wr = wid >> 1, wc = wid & 1;   // wave tile 64x64

  const int sub0  = wid >> 1;              // staging sub base
  const int rowl  = (wid & 1) * 64 + lane;
  int rowA = mb * BM + rowl;
  if (rowA > NROW - 1) rowA = NROW - 1;    // clamp; excluded from stats/store
  const unsigned short* gA = hcat + (long)rowA * KDIM;
  const unsigned short* gB = wbf + (long)(nb * BN + rowl) * KDIM;
  const int dBase = (wid & 1) * 512;       // ushort idx; + sub*1024 per round

  f32x4 acc[4][4];
#pragma unroll
  for (int i = 0; i < 4; ++i)
#pragma unroll
    for (int j = 0; j < 4; ++j) acc[i][j] = (f32x4){0.f, 0.f, 0.f, 0.f};

  const int koff = lane >> 4;
  const int r16 = lane & 15;

  for (int kt = 0; kt < KDIM; kt += BK) {
#pragma unroll
    for (int j = 0; j < 4; ++j) {
      const int sub = sub0 + 2 * j;
      gload_lds16(gA + kt + sub * 8, &ldsA[sub * 1024 + dBase]);
      gload_lds16(gB + kt + sub * 8, &ldsB[sub * 1024 + dBase]);
    }
    __syncthreads();

    bf16x8 af[2][4], bfr[2][4];
#pragma unroll
    for (int ks = 0; ks < 2; ++ks) {
#pragma unroll
      for (int mf = 0; mf < 4; ++mf)
        af[ks][mf] = *(const bf16x8*)
            &ldsA[ks * 4096 + koff * 1024 + (wr * 64 + mf * 16 + r16) * 8];
#pragma unroll
      for (int nf = 0; nf < 4; ++nf)
        bfr[ks][nf] = *(const bf16x8*)
            &ldsB[ks * 4096 + koff * 1024 + (wc * 64 + nf * 16 + r16) * 8];
    }
#pragma unroll
    for (int ks = 0; ks < 2; ++ks)
#pragma unroll
      for (int mf = 0; mf < 4; ++mf)
#pragma unroll
        for (int nf = 0; nf < 4; ++nf)
          acc[mf][nf] = __builtin_amdgcn_mfma_f32_16x16x32_bf16(
              af[ks][mf], bfr[ks][nf], acc[mf][nf], 0, 0, 0);
    __syncthreads();
  }

  // epilogue: C/D layout col=lane&15, row=(lane>>4)*4+reg; fused BN stats
  const int rgrp = lane >> 4;
#pragma unroll
  for (int nf = 0; nf < 4; ++nf) {
    const int col = nb * BN + wc * 64 + nf * 16 + r16;
    const float bv = bias[col];
    float s = 0.f, q = 0.f;
#pragma unroll
    for (int mf = 0; mf < 4; ++mf) {
#pragma unroll
      for (int r = 0; r < 4; ++r) {
        const int m = mb * BM + wr * 64 + mf * 16 + rgrp * 4 + r;
        float v = acc[mf][nf][r] + bv;
        v = fmaxf(v, 0.f);
        if (m < NROW) {
          h[(long)m * D + col] = v;
          s += v;
          q += v * v;
        }
      }
    }
    s += __shfl_xor(s, 16); s += __shfl_xor(s, 32);
    q += __shfl_xor(q, 16); q += __shfl_xor(q, 32);
    if (rgrp == 0) {
      atomicAdd(&csum[col], s);
      atomicAdd(&csq[col], q);
    }
  }
}

// K3: BN apply + row L2 normalize; wave-per-row, hoisted column params
__launch_bounds__(256)
__global__ void finalize_kernel(const float* __restrict__ h,
                                const float* __restrict__ csum,
                                const float* __restrict__ csq,
                                const float* __restrict__ gamma,
                                const float* __restrict__ beta,
                                float* __restrict__ out) {
  const int lane = threadIdx.x & 63, wid = threadIdx.x >> 6;
  const int c0 = lane * 8;

  float mu[8], g[8], be[8];
#pragma unroll
  for (int j = 0; j < 8; ++j) {
    const int c = c0 + j;
    const float m = csum[c] * (1.0f / NROW);
    float var = csq[c] * (1.0f / NROW) - m * m;
    var = fmaxf(var, 0.f);
    mu[j] = m;
    g[j]  = rsqrtf(var + 1e-5f) * gamma[c];
    be[j] = beta[c];
  }

  for (int r = blockIdx.x * 4 + wid; r < NROW; r += gridDim.x * 4) {
    const float* hp = h + (long)r * D + c0;
    float4 x0 = *(const float4*)(hp);
    float4 x1 = *(const float4*)(hp + 4);
    float y[8];
    y[0] = (x0.x - mu[0]) * g[0] + be[0];
    y[1] = (x0.y - mu[1]) * g[1] + be[1];
    y[2] = (x0.z - mu[2]) * g[2] + be[2];
    y[3] = (x0.w - mu[3]) * g[3] + be[3];
    y[4] = (x1.x - mu[4]) * g[4] + be[4];
    y[5] = (x1.y - mu[5]) * g[5] + be[5];
    y[6] = (x1.z - mu[6]) * g[6] + be[6];
    y[7] = (x1.w - mu[7]) * g[7] + be[7];
    float ss = 0.f;
#pragma unroll
    for (int j = 0; j < 8; ++j) ss += y[j] * y[j];
#pragma unroll
    for (int off = 32; off > 0; off >>= 1) ss += __shfl_xor(ss, off);
    const float sc = 1.0f / (sqrtf(ss) + 1e-6f);
    float4 o0, o1;
    o0.x = y[0] * sc; o0.y = y[1] * sc; o0.z = y[2] * sc; o0.w = y[3] * sc;
    o1.x = y[4] * sc; o1.y = y[5] * sc; o1.z = y[6] * sc; o1.w = y[7] * sc;
    float* op = out + (long)r * D + c0;
    *(float4*)(op) = o0;
    *(float4*)(op + 4) = o1;
  }
}

extern "C" void kernel_launch(void* const* d_in, const int* in_sizes, int n_in,
                              void* d_out, int out_size, void* d_ws, size_t ws_size,
                              hipStream_t stream) {
  const float* feat  = (const float*)d_in[0];
  const float* W     = (const float*)d_in[1];
  const float* bias  = (const float*)d_in[2];
  const float* gamma = (const float*)d_in[3];
  const float* beta  = (const float*)d_in[4];
  const int* self_idx = (const int*)d_in[5];
  const int* neigh    = (const int*)d_in[6];
  float* out = (float*)d_out;

  char* ws = (char*)d_ws;
  unsigned short* fbf  = (unsigned short*)(ws);                    // 40,960,000 B
  unsigned short* wbf  = (unsigned short*)(ws + 40960000);         //  1,048,576 B
  unsigned short* hcat = (unsigned short*)(ws + 42008576);         // 40,960,000 B
  float* h    = (float*)(ws + 82968576);                           // 40,960,000 B
  float* csum = (float*)(ws + 123928576);                          // 2048 B
  float* csq  = (float*)(ws + 123930624);                          // 2048 B

  hipMemsetAsync(csum, 0, 4096, stream);
  convert_kernel<<<2048, 256, 0, stream>>>(feat, W, fbf, wbf);
  gather_kernel<<<(NROW + 3) / 4, 256, 0, stream>>>(fbf, self_idx, neigh, hcat);
  gemm_kernel<<<dim3((NROW + BM - 1) / BM, D / BN), 256, 0, stream>>>(hcat, wbf, bias, h, csum, csq);
  finalize_kernel<<<1250, 256, 0, stream>>>(h, csum, csq, gamma, beta, out);
}

// Round 5
// 308.879 us; speedup vs baseline: 1.0520x; 1.0520x over previous
//
#include <hip/hip_runtime.h>
#include <hip/hip_bf16.h>
#include <stdint.h>

#define N_TOTAL 40000
#define NROW    20000
#define D       512
#define NSAMP   25
#define KDIM    1024   // 2*D
#define BM      64
#define BN      128
#define BK      32
#define NT      (KDIM / BK)   // 32 K-steps

typedef __bf16 bf16x8 __attribute__((ext_vector_type(8)));
typedef float  f32x4  __attribute__((ext_vector_type(4)));

__device__ inline float bf2f(unsigned short u) {
  union { uint32_t u; float f; } cv; cv.u = ((uint32_t)u) << 16; return cv.f;
}
__device__ inline unsigned short f2bf(float f) {
  union { float f; uint32_t u; } cv; cv.f = f;
  uint32_t u = cv.u;
  uint32_t r = (u + 0x7fffu + ((u >> 16) & 1u)) >> 16;  // RNE
  return (unsigned short)r;
}

__device__ inline void gload_lds16(const void* gsrc, void* ldst) {
  __builtin_amdgcn_global_load_lds(
      (const __attribute__((address_space(1))) uint32_t*)gsrc,
      (__attribute__((address_space(3))) uint32_t*)ldst,
      16, 0, 0);
}

// K0: convert features (f32->bf16) and W (f32->bf16)
__global__ void convert_kernel(const float* __restrict__ feat,
                               const float* __restrict__ W,
                               unsigned short* __restrict__ fbf,
                               unsigned short* __restrict__ wbf) {
  const int NF = N_TOTAL * D;      // 20,480,000
  const int NW = D * KDIM;         // 524,288
  const int total4 = (NF + NW) >> 2;
  for (int i = blockIdx.x * blockDim.x + threadIdx.x; i < total4;
       i += gridDim.x * blockDim.x) {
    int e = i << 2;
    float4 v;
    unsigned short* dst;
    if (e < NF) { v = *(const float4*)(feat + e); dst = fbf + e; }
    else        { int e2 = e - NF; v = *(const float4*)(W + e2); dst = wbf + e2; }
    ushort4 o;
    o.x = f2bf(v.x); o.y = f2bf(v.y); o.z = f2bf(v.z); o.w = f2bf(v.w);
    *(ushort4*)dst = o;
  }
}

// K1: gather self row + mean of 25 neighbor rows -> hcat bf16 [NROW][1024]
__launch_bounds__(256, 3)
__global__ void gather_kernel(const unsigned short* __restrict__ fbf,
                              const int* __restrict__ self_idx,
                              const int* __restrict__ neigh_idx,
                              unsigned short* __restrict__ hcat) {
  const int wid = threadIdx.x >> 6;
  const int lane = threadIdx.x & 63;
  const int n = blockIdx.x * 4 + wid;
  if (n >= NROW) return;
  const int col8 = lane * 8;   // 8 bf16 per lane covers 512 cols

  int si = __builtin_amdgcn_readfirstlane(self_idx[n]);
  uint4 sv = *(const uint4*)(fbf + (long)si * D + col8);
  *(uint4*)(hcat + (long)n * KDIM + col8) = sv;

  int idx[NSAMP];
#pragma unroll
  for (int s = 0; s < NSAMP; ++s)
    idx[s] = __builtin_amdgcn_readfirstlane(neigh_idx[n * NSAMP + s]);

  uint4 v[NSAMP];
#pragma unroll
  for (int s = 0; s < NSAMP; ++s)
    v[s] = *(const uint4*)(fbf + (long)idx[s] * D + col8);

  float acc[8];
#pragma unroll
  for (int j = 0; j < 8; ++j) acc[j] = 0.f;
#pragma unroll
  for (int s = 0; s < NSAMP; ++s) {
    const unsigned short* u = (const unsigned short*)&v[s];
#pragma unroll
    for (int j = 0; j < 8; ++j) acc[j] += bf2f(u[j]);
  }
  unsigned short ob[8];
#pragma unroll
  for (int j = 0; j < 8; ++j) ob[j] = f2bf(acc[j] * (1.0f / NSAMP));
  *(uint4*)(hcat + (long)n * KDIM + D + col8) = *(uint4*)ob;
}

// K2: h = relu(hcat @ W^T + b), BM=64 x BN=128, BK=32, 4 waves.
// Double-buffered LDS, counted vmcnt (loads span barriers), fused BN stats.
// LDS per buf (ushort idx): A [koff 0..3][row 0..63][8] = 2048, B [koff][row 0..127][8] = 4096.
__launch_bounds__(256)
__global__ void gemm_kernel(const unsigned short* __restrict__ hcat,
                            const unsigned short* __restrict__ wbf,
                            const float* __restrict__ bias,
                            float* __restrict__ h,
                            float* __restrict__ csum,
                            float* __restrict__ csq) {
  __shared__ unsigned short lds[12288];   // 24 KB: 2 bufs x 6144 ushorts
  const int tid = threadIdx.x;
  const int lane = tid & 63, wid = tid >> 6;
  const int nb = blockIdx.x, mb = blockIdx.y;   // nb fast-varying: A-tile reuse in L2/L3
  const int wr = wid >> 1, wc = wid & 1;        // wave tile 32x64

  // A staging: thread t -> row t&63, k-group t>>6 (== wid)
  int rowA = mb * BM + (tid & 63);
  if (rowA > NROW - 1) rowA = NROW - 1;         // clamp; excluded from stats/store
  const unsigned short* gA = hcat + (long)rowA * KDIM + (tid >> 6) * 8;
  // B staging: 2 loads: row t&127, k-groups (t>>7) and 2+(t>>7)
  const unsigned short* gB = wbf + (long)(nb * BN + (tid & 127)) * KDIM + (tid >> 7) * 8;
  // LDS staging bases (ushort idx), wave-uniform; lane*16B added by HW
  const int sA  = wid * 512;
  const int sB0 = 2048 + wid * 512;
  const int sB1 = 4096 + wid * 512;

  f32x4 acc[2][4];
#pragma unroll
  for (int i = 0; i < 2; ++i)
#pragma unroll
    for (int j = 0; j < 4; ++j) acc[i][j] = (f32x4){0.f, 0.f, 0.f, 0.f};

  const int koff = lane >> 4;   // 0..3
  const int r16 = lane & 15;

#define STAGE(buf, kt)                                        \
  do {                                                        \
    gload_lds16(gA + (kt),      &lds[(buf) * 6144 + sA]);     \
    gload_lds16(gB + (kt),      &lds[(buf) * 6144 + sB0]);    \
    gload_lds16(gB + (kt) + 16, &lds[(buf) * 6144 + sB1]);    \
  } while (0)

  STAGE(0, 0);
  int cur = 0;
  for (int t = 0; t < NT; ++t) {
    if (t + 1 < NT) {
      STAGE(cur ^ 1, (t + 1) * BK);
      asm volatile("s_waitcnt vmcnt(3)" ::: "memory");  // wait cur buf; keep next in flight
    } else {
      asm volatile("s_waitcnt vmcnt(0)" ::: "memory");
    }
    __builtin_amdgcn_s_barrier();

    bf16x8 af[2], bfr[4];
    {
      const int aOff = cur * 6144 + koff * 512 + (wr * 32 + r16) * 8;
#pragma unroll
      for (int mf = 0; mf < 2; ++mf)
        af[mf] = *(const bf16x8*)&lds[aOff + mf * 128];
      const int bOff = cur * 6144 + 2048 + koff * 1024 + (wc * 64 + r16) * 8;
#pragma unroll
      for (int nf = 0; nf < 4; ++nf)
        bfr[nf] = *(const bf16x8*)&lds[bOff + nf * 128];
    }
#pragma unroll
    for (int mf = 0; mf < 2; ++mf)
#pragma unroll
      for (int nf = 0; nf < 4; ++nf)
        acc[mf][nf] = __builtin_amdgcn_mfma_f32_16x16x32_bf16(
            af[mf], bfr[nf], acc[mf][nf], 0, 0, 0);

    __builtin_amdgcn_s_barrier();   // all waves done reading cur before it is re-staged
    cur ^= 1;
  }
#undef STAGE

  // epilogue: C/D layout col=lane&15, row=(lane>>4)*4+reg; fused BN stats
  const int rgrp = lane >> 4;
#pragma unroll
  for (int nf = 0; nf < 4; ++nf) {
    const int col = nb * BN + wc * 64 + nf * 16 + r16;
    const float bv = bias[col];
    float s = 0.f, q = 0.f;
#pragma unroll
    for (int mf = 0; mf < 2; ++mf) {
#pragma unroll
      for (int r = 0; r < 4; ++r) {
        const int m = mb * BM + wr * 32 + mf * 16 + rgrp * 4 + r;
        float v = acc[mf][nf][r] + bv;
        v = fmaxf(v, 0.f);
        if (m < NROW) {
          h[(long)m * D + col] = v;
          s += v;
          q += v * v;
        }
      }
    }
    s += __shfl_xor(s, 16); s += __shfl_xor(s, 32);
    q += __shfl_xor(q, 16); q += __shfl_xor(q, 32);
    if (rgrp == 0) {
      atomicAdd(&csum[col], s);
      atomicAdd(&csq[col], q);
    }
  }
}

// K3: BN apply + row L2 normalize; wave-per-row, hoisted column params
__launch_bounds__(256)
__global__ void finalize_kernel(const float* __restrict__ h,
                                const float* __restrict__ csum,
                                const float* __restrict__ csq,
                                const float* __restrict__ gamma,
                                const float* __restrict__ beta,
                                float* __restrict__ out) {
  const int lane = threadIdx.x & 63, wid = threadIdx.x >> 6;
  const int c0 = lane * 8;

  float mu[8], g[8], be[8];
#pragma unroll
  for (int j = 0; j < 8; ++j) {
    const int c = c0 + j;
    const float m = csum[c] * (1.0f / NROW);
    float var = csq[c] * (1.0f / NROW) - m * m;
    var = fmaxf(var, 0.f);
    mu[j] = m;
    g[j]  = rsqrtf(var + 1e-5f) * gamma[c];
    be[j] = beta[c];
  }

  for (int r = blockIdx.x * 4 + wid; r < NROW; r += gridDim.x * 4) {
    const float* hp = h + (long)r * D + c0;
    float4 x0 = *(const float4*)(hp);
    float4 x1 = *(const float4*)(hp + 4);
    float y[8];
    y[0] = (x0.x - mu[0]) * g[0] + be[0];
    y[1] = (x0.y - mu[1]) * g[1] + be[1];
    y[2] = (x0.z - mu[2]) * g[2] + be[2];
    y[3] = (x0.w - mu[3]) * g[3] + be[3];
    y[4] = (x1.x - mu[4]) * g[4] + be[4];
    y[5] = (x1.y - mu[5]) * g[5] + be[5];
    y[6] = (x1.z - mu[6]) * g[6] + be[6];
    y[7] = (x1.w - mu[7]) * g[7] + be[7];
    float ss = 0.f;
#pragma unroll
    for (int j = 0; j < 8; ++j) ss += y[j] * y[j];
#pragma unroll
    for (int off = 32; off > 0; off >>= 1) ss += __shfl_xor(ss, off);
    const float sc = 1.0f / (sqrtf(ss) + 1e-6f);
    float4 o0, o1;
    o0.x = y[0] * sc; o0.y = y[1] * sc; o0.z = y[2] * sc; o0.w = y[3] * sc;
    o1.x = y[4] * sc; o1.y = y[5] * sc; o1.z = y[6] * sc; o1.w = y[7] * sc;
    float* op = out + (long)r * D + c0;
    *(float4*)(op) = o0;
    *(float4*)(op + 4) = o1;
  }
}

extern "C" void kernel_launch(void* const* d_in, const int* in_sizes, int n_in,
                              void* d_out, int out_size, void* d_ws, size_t ws_size,
                              hipStream_t stream) {
  const float* feat  = (const float*)d_in[0];
  const float* W     = (const float*)d_in[1];
  const float* bias  = (const float*)d_in[2];
  const float* gamma = (const float*)d_in[3];
  const float* beta  = (const float*)d_in[4];
  const int* self_idx = (const int*)d_in[5];
  const int* neigh    = (const int*)d_in[6];
  float* out = (float*)d_out;

  char* ws = (char*)d_ws;
  unsigned short* fbf  = (unsigned short*)(ws);                    // 40,960,000 B
  unsigned short* wbf  = (unsigned short*)(ws + 40960000);         //  1,048,576 B
  unsigned short* hcat = (unsigned short*)(ws + 42008576);         // 40,960,000 B
  float* h    = (float*)(ws + 82968576);                           // 40,960,000 B
  float* csum = (float*)(ws + 123928576);                          // 2048 B
  float* csq  = (float*)(ws + 123930624);                          // 2048 B

  hipMemsetAsync(csum, 0, 4096, stream);
  convert_kernel<<<2048, 256, 0, stream>>>(feat, W, fbf, wbf);
  gather_kernel<<<(NROW + 3) / 4, 256, 0, stream>>>(fbf, self_idx, neigh, hcat);
  gemm_kernel<<<dim3(D / BN, (NROW + BM - 1) / BM), 256, 0, stream>>>(hcat, wbf, bias, h, csum, csq);
  finalize_kernel<<<1250, 256, 0, stream>>>(h, csum, csq, gamma, beta, out);
}

// Round 7
// 301.727 us; speedup vs baseline: 1.0769x; 1.0237x over previous
//
#include <hip/hip_runtime.h>
#include <hip/hip_bf16.h>
#include <stdint.h>

#define N_TOTAL 40000
#define NROW    20000
#define D       512
#define NSAMP   25
#define KDIM    1024   // 2*D
#define BM      64
#define BN      128
#define BK      32
#define NT      (KDIM / BK)   // 32 K-steps
#define MBLKS   ((NROW + BM - 1) / BM)   // 313

typedef __bf16 bf16x8 __attribute__((ext_vector_type(8)));
typedef float  f32x4  __attribute__((ext_vector_type(4)));

__device__ inline float bf2f(unsigned short u) {
  union { uint32_t u; float f; } cv; cv.u = ((uint32_t)u) << 16; return cv.f;
}
__device__ inline unsigned short f2bf(float f) {
  union { float f; uint32_t u; } cv; cv.f = f;
  uint32_t u = cv.u;
  uint32_t r = (u + 0x7fffu + ((u >> 16) & 1u)) >> 16;  // RNE
  return (unsigned short)r;
}

__device__ inline void gload_lds16(const void* gsrc, void* ldst) {
  __builtin_amdgcn_global_load_lds(
      (const __attribute__((address_space(1))) uint32_t*)gsrc,
      (__attribute__((address_space(3))) uint32_t*)ldst,
      16, 0, 0);
}

// K0: convert features (f32->bf16) and W (f32->bf16)
__global__ void convert_kernel(const float* __restrict__ feat,
                               const float* __restrict__ W,
                               unsigned short* __restrict__ fbf,
                               unsigned short* __restrict__ wbf) {
  const int NF = N_TOTAL * D;      // 20,480,000
  const int NW = D * KDIM;         // 524,288
  const int total4 = (NF + NW) >> 2;
  for (int i = blockIdx.x * blockDim.x + threadIdx.x; i < total4;
       i += gridDim.x * blockDim.x) {
    int e = i << 2;
    float4 v;
    unsigned short* dst;
    if (e < NF) { v = *(const float4*)(feat + e); dst = fbf + e; }
    else        { int e2 = e - NF; v = *(const float4*)(W + e2); dst = wbf + e2; }
    ushort4 o;
    o.x = f2bf(v.x); o.y = f2bf(v.y); o.z = f2bf(v.z); o.w = f2bf(v.w);
    *(ushort4*)dst = o;
  }
}

// K1: gather self row + mean of 25 neighbor rows -> hcat bf16 [NROW][1024]
__launch_bounds__(256, 3)
__global__ void gather_kernel(const unsigned short* __restrict__ fbf,
                              const int* __restrict__ self_idx,
                              const int* __restrict__ neigh_idx,
                              unsigned short* __restrict__ hcat) {
  const int wid = threadIdx.x >> 6;
  const int lane = threadIdx.x & 63;
  const int n = blockIdx.x * 4 + wid;
  if (n >= NROW) return;
  const int col8 = lane * 8;   // 8 bf16 per lane covers 512 cols

  int si = __builtin_amdgcn_readfirstlane(self_idx[n]);
  uint4 sv = *(const uint4*)(fbf + (long)si * D + col8);
  *(uint4*)(hcat + (long)n * KDIM + col8) = sv;

  int idx[NSAMP];
#pragma unroll
  for (int s = 0; s < NSAMP; ++s)
    idx[s] = __builtin_amdgcn_readfirstlane(neigh_idx[n * NSAMP + s]);

  uint4 v[NSAMP];
#pragma unroll
  for (int s = 0; s < NSAMP; ++s)
    v[s] = *(const uint4*)(fbf + (long)idx[s] * D + col8);

  float acc[8];
#pragma unroll
  for (int j = 0; j < 8; ++j) acc[j] = 0.f;
#pragma unroll
  for (int s = 0; s < NSAMP; ++s) {
    const unsigned short* u = (const unsigned short*)&v[s];
#pragma unroll
    for (int j = 0; j < 8; ++j) acc[j] += bf2f(u[j]);
  }
  unsigned short ob[8];
#pragma unroll
  for (int j = 0; j < 8; ++j) ob[j] = f2bf(acc[j] * (1.0f / NSAMP));
  *(uint4*)(hcat + (long)n * KDIM + D + col8) = *(uint4*)ob;
}

// K2: h = relu(hcat @ W^T + b) -> bf16, BM=64 x BN=128, BK=32, 4 waves.
// 3-deep LDS pipeline (counted vmcnt(6)), XCD-swizzled grid (mb%8 -> XCD),
// fused BN column stats. LDS per buf (ushort idx): A [koff][row64][8]=2048,
// B [koff][row128][8]=4096.
__launch_bounds__(256)
__global__ void gemm_kernel(const unsigned short* __restrict__ hcat,
                            const unsigned short* __restrict__ wbf,
                            const float* __restrict__ bias,
                            unsigned short* __restrict__ hbf,
                            float* __restrict__ csum,
                            float* __restrict__ csq) {
  __shared__ unsigned short lds[18432];   // 36 KB: 3 bufs x 6144 ushorts
  const int wg = blockIdx.x;
  const int xcd = wg & 7, pos = wg >> 3;
  const int mb = xcd + 8 * (pos >> 2);    // 4 nb-blocks of an mb share an XCD
  const int nb = pos & 3;
  if (mb >= MBLKS) return;

  const int tid = threadIdx.x;
  const int lane = tid & 63, wid = tid >> 6;
  const int wr = wid >> 1, wc = wid & 1;  // wave tile 32x64

  int rowA = mb * BM + (tid & 63);
  if (rowA > NROW - 1) rowA = NROW - 1;   // clamp; excluded from stats/store
  const unsigned short* gA = hcat + (long)rowA * KDIM + (tid >> 6) * 8;
  const unsigned short* gB = wbf + (long)(nb * BN + (tid & 127)) * KDIM + (tid >> 7) * 8;
  const int sA  = wid * 512;
  const int sB0 = 2048 + wid * 512;
  const int sB1 = 4096 + wid * 512;

  f32x4 acc[2][4];
#pragma unroll
  for (int i = 0; i < 2; ++i)
#pragma unroll
    for (int j = 0; j < 4; ++j) acc[i][j] = (f32x4){0.f, 0.f, 0.f, 0.f};

  const int koff = lane >> 4;   // 0..3
  const int r16 = lane & 15;

#define STAGE(buf, kt)                                        \
  do {                                                        \
    gload_lds16(gA + (kt),      &lds[(buf) * 6144 + sA]);     \
    gload_lds16(gB + (kt),      &lds[(buf) * 6144 + sB0]);    \
    gload_lds16(gB + (kt) + 16, &lds[(buf) * 6144 + sB1]);    \
  } while (0)

#define COMPUTE(BC)                                                          \
  do {                                                                       \
    bf16x8 af0, af1, bf0, bf1, bf2, bf3;                                     \
    const int aOff = (BC) * 6144 + koff * 512 + (wr * 32 + r16) * 8;         \
    af0 = *(const bf16x8*)&lds[aOff];                                        \
    af1 = *(const bf16x8*)&lds[aOff + 128];                                  \
    const int bOff = (BC) * 6144 + 2048 + koff * 1024 + (wc * 64 + r16) * 8; \
    bf0 = *(const bf16x8*)&lds[bOff];                                        \
    bf1 = *(const bf16x8*)&lds[bOff + 128];                                  \
    bf2 = *(const bf16x8*)&lds[bOff + 256];                                  \
    bf3 = *(const bf16x8*)&lds[bOff + 384];                                  \
    acc[0][0] = __builtin_amdgcn_mfma_f32_16x16x32_bf16(af0, bf0, acc[0][0], 0, 0, 0); \
    acc[0][1] = __builtin_amdgcn_mfma_f32_16x16x32_bf16(af0, bf1, acc[0][1], 0, 0, 0); \
    acc[0][2] = __builtin_amdgcn_mfma_f32_16x16x32_bf16(af0, bf2, acc[0][2], 0, 0, 0); \
    acc[0][3] = __builtin_amdgcn_mfma_f32_16x16x32_bf16(af0, bf3, acc[0][3], 0, 0, 0); \
    acc[1][0] = __builtin_amdgcn_mfma_f32_16x16x32_bf16(af1, bf0, acc[1][0], 0, 0, 0); \
    acc[1][1] = __builtin_amdgcn_mfma_f32_16x16x32_bf16(af1, bf1, acc[1][1], 0, 0, 0); \
    acc[1][2] = __builtin_amdgcn_mfma_f32_16x16x32_bf16(af1, bf2, acc[1][2], 0, 0, 0); \
    acc[1][3] = __builtin_amdgcn_mfma_f32_16x16x32_bf16(af1, bf3, acc[1][3], 0, 0, 0); \
  } while (0)

#define STEP(T, BC, BS)                                                       \
  do {                                                                        \
    if ((T) < NT) {                                                           \
      if ((T) + 2 < NT) {                                                     \
        STAGE(BS, ((T) + 2) * BK);                                            \
        asm volatile("s_waitcnt vmcnt(6)" ::: "memory");                      \
      } else if ((T) + 1 < NT) {                                              \
        asm volatile("s_waitcnt vmcnt(3)" ::: "memory");                      \
      } else {                                                                \
        asm volatile("s_waitcnt vmcnt(0)" ::: "memory");                      \
      }                                                                       \
      __builtin_amdgcn_s_barrier();                                           \
      COMPUTE(BC);                                                            \
      __builtin_amdgcn_s_barrier();                                           \
    }                                                                         \
  } while (0)

  STAGE(0, 0);
  STAGE(1, BK);
  for (int t = 0; t < NT; t += 3) {
    STEP(t,     0, 2);
    STEP(t + 1, 1, 0);
    STEP(t + 2, 2, 1);
  }
#undef STEP
#undef COMPUTE
#undef STAGE

  // epilogue: C/D layout col=lane&15, row=(lane>>4)*4+reg; fused BN stats
  const int rgrp = lane >> 4;
#pragma unroll
  for (int nf = 0; nf < 4; ++nf) {
    const int col = nb * BN + wc * 64 + nf * 16 + r16;
    const float bv = bias[col];
    float s = 0.f, q = 0.f;
#pragma unroll
    for (int mf = 0; mf < 2; ++mf) {
#pragma unroll
      for (int r = 0; r < 4; ++r) {
        const int m = mb * BM + wr * 32 + mf * 16 + rgrp * 4 + r;
        float v = acc[mf][nf][r] + bv;
        v = fmaxf(v, 0.f);
        if (m < NROW) {
          hbf[(long)m * D + col] = f2bf(v);
          s += v;
          q += v * v;
        }
      }
    }
    s += __shfl_xor(s, 16); s += __shfl_xor(s, 32);
    q += __shfl_xor(q, 16); q += __shfl_xor(q, 32);
    if (rgrp == 0) {
      atomicAdd(&csum[col], s);
      atomicAdd(&csq[col], q);
    }
  }
}

// K3: BN apply + row L2 normalize; wave-per-row, bf16 h input, hoisted params
__launch_bounds__(256)
__global__ void finalize_kernel(const unsigned short* __restrict__ hbf,
                                const float* __restrict__ csum,
                                const float* __restrict__ csq,
                                const float* __restrict__ gamma,
                                const float* __restrict__ beta,
                                float* __restrict__ out) {
  const int lane = threadIdx.x & 63, wid = threadIdx.x >> 6;
  const int c0 = lane * 8;

  float mu[8], g[8], be[8];
#pragma unroll
  for (int j = 0; j < 8; ++j) {
    const int c = c0 + j;
    const float m = csum[c] * (1.0f / NROW);
    float var = csq[c] * (1.0f / NROW) - m * m;
    var = fmaxf(var, 0.f);
    mu[j] = m;
    g[j]  = rsqrtf(var + 1e-5f) * gamma[c];
    be[j] = beta[c];
  }

  for (int r = blockIdx.x * 4 + wid; r < NROW; r += gridDim.x * 4) {
    uint4 hv = *(const uint4*)(hbf + (long)r * D + c0);
    const unsigned short* hu = (const unsigned short*)&hv;
    float y[8];
#pragma unroll
    for (int j = 0; j < 8; ++j) y[j] = (bf2f(hu[j]) - mu[j]) * g[j] + be[j];
    float ss = 0.f;
#pragma unroll
    for (int j = 0; j < 8; ++j) ss += y[j] * y[j];
#pragma unroll
    for (int off = 32; off > 0; off >>= 1) ss += __shfl_xor(ss, off);
    const float sc = 1.0f / (sqrtf(ss) + 1e-6f);
    float4 o0, o1;
    o0.x = y[0] * sc; o0.y = y[1] * sc; o0.z = y[2] * sc; o0.w = y[3] * sc;
    o1.x = y[4] * sc; o1.y = y[5] * sc; o1.z = y[6] * sc; o1.w = y[7] * sc;
    float* op = out + (long)r * D + c0;
    *(float4*)(op) = o0;
    *(float4*)(op + 4) = o1;
  }
}

extern "C" void kernel_launch(void* const* d_in, const int* in_sizes, int n_in,
                              void* d_out, int out_size, void* d_ws, size_t ws_size,
                              hipStream_t stream) {
  const float* feat  = (const float*)d_in[0];
  const float* W     = (const float*)d_in[1];
  const float* bias  = (const float*)d_in[2];
  const float* gamma = (const float*)d_in[3];
  const float* beta  = (const float*)d_in[4];
  const int* self_idx = (const int*)d_in[5];
  const int* neigh    = (const int*)d_in[6];
  float* out = (float*)d_out;

  char* ws = (char*)d_ws;
  unsigned short* fbf  = (unsigned short*)(ws);                    // 40,960,000 B
  unsigned short* wbf  = (unsigned short*)(ws + 40960000);         //  1,048,576 B
  unsigned short* hcat = (unsigned short*)(ws + 42008576);         // 40,960,000 B
  unsigned short* hbf  = (unsigned short*)(ws + 82968576);         // 20,480,000 B
  float* csum = (float*)(ws + 123928576);                          // 2048 B
  float* csq  = (float*)(ws + 123930624);                          // 2048 B

  hipMemsetAsync(csum, 0, 4096, stream);
  convert_kernel<<<2048, 256, 0, stream>>>(feat, W, fbf, wbf);
  gather_kernel<<<(NROW + 3) / 4, 256, 0, stream>>>(fbf, self_idx, neigh, hcat);
  gemm_kernel<<<8 * 4 * 40, 256, 0, stream>>>(hcat, wbf, bias, hbf, csum, csq);
  finalize_kernel<<<1250, 256, 0, stream>>>(hbf, csum, csq, gamma, beta, out);
}

// Round 8
// 275.640 us; speedup vs baseline: 1.1789x; 1.0946x over previous
//
#include <hip/hip_runtime.h>
#include <hip/hip_bf16.h>
#include <stdint.h>

#define N_TOTAL 40000
#define NROW    20000
#define D       512
#define NSAMP   25
#define KDIM    1024   // 2*D
#define BM      128
#define BN      128
#define BK      32
#define NT      (KDIM / BK)              // 32 K-steps
#define MBLKS   ((NROW + BM - 1) / BM)   // 157

typedef __bf16 bf16x8 __attribute__((ext_vector_type(8)));
typedef float  f32x4  __attribute__((ext_vector_type(4)));

__device__ inline float bf2f(unsigned short u) {
  union { uint32_t u; float f; } cv; cv.u = ((uint32_t)u) << 16; return cv.f;
}
__device__ inline unsigned short f2bf(float f) {
  union { float f; uint32_t u; } cv; cv.f = f;
  uint32_t u = cv.u;
  uint32_t r = (u + 0x7fffu + ((u >> 16) & 1u)) >> 16;  // RNE
  return (unsigned short)r;
}

// f32 -> e4m3fn (RNE, saturating). Inputs are N(0,1) — no overflow path hit.
__device__ inline unsigned char f2e4m3(float f) {
  union { float f; uint32_t u; } cv; cv.f = f;
  uint32_t u = cv.u;
  uint32_t s = (u >> 24) & 0x80;
  float a = fabsf(f);
  if (a < 0.001953125f) {              // < 2^-9: rounds toward 0/denorm region
    // denorm: value = m * 2^-9, m = round(a * 512)
    uint32_t m = (uint32_t)(a * 512.0f + 0.5f);
    return (unsigned char)(s | m);
  }
  if (a > 448.0f) return (unsigned char)(s | 0x7E);  // saturate to 448
  // normal: round mantissa to 3 bits via float add trick
  int e = (int)((u >> 23) & 0xFF) - 127;             // a >= 2^-9 -> e >= -9
  if (e < -6) {                                      // denorm range 2^-9..2^-6
    uint32_t m = (uint32_t)(a * 512.0f + 0.5f);      // 1..7 (may carry to 8)
    if (m >= 8) return (unsigned char)(s | 0x08);    // rounds up to 2^-6
    return (unsigned char)(s | m);
  }
  // RNE on 3-bit mantissa
  uint32_t mant = u & 0x7FFFFF;
  uint32_t keep = mant >> 20;
  uint32_t rest = mant & 0xFFFFF;
  uint32_t half = 0x80000;
  if (rest > half || (rest == half && (keep & 1))) {
    keep++;
    if (keep == 8) { keep = 0; e++; if (e > 8) return (unsigned char)(s | 0x7E); }
  }
  return (unsigned char)(s | ((uint32_t)(e + 7) << 3) | keep);
}

// e4m3fn -> f32, denorms approximated as normals (error analysis in notes)
__device__ inline void acc_fp8x4(uint32_t w, float* acc) {
#pragma unroll
  for (int j = 0; j < 4; ++j) {
    uint32_t b = (w >> (8 * j)) & 0xFF;
    uint32_t t = b & 0x7F;
    uint32_t bits = (t << 20) + 0x3C000000;   // (e+120)<<23 | m<<20
    bits |= (b & 0x80) << 24;
    union { uint32_t u; float f; } cv; cv.u = bits;
    acc[j] += cv.f;
  }
}

__device__ inline void gload_lds16(const void* gsrc, void* ldst) {
  __builtin_amdgcn_global_load_lds(
      (const __attribute__((address_space(1))) uint32_t*)gsrc,
      (__attribute__((address_space(3))) uint32_t*)ldst,
      16, 0, 0);
}

// K0: features f32 -> bf16 (fbf) AND e4m3 (f8); W f32 -> bf16 (wbf)
__global__ void convert_kernel(const float* __restrict__ feat,
                               const float* __restrict__ W,
                               unsigned short* __restrict__ fbf,
                               unsigned short* __restrict__ wbf,
                               unsigned char* __restrict__ f8) {
  const int NF = N_TOTAL * D;      // 20,480,000
  const int NW = D * KDIM;         // 524,288
  const int total4 = (NF + NW) >> 2;
  for (int i = blockIdx.x * blockDim.x + threadIdx.x; i < total4;
       i += gridDim.x * blockDim.x) {
    int e = i << 2;
    if (e < NF) {
      float4 v = *(const float4*)(feat + e);
      ushort4 o;
      o.x = f2bf(v.x); o.y = f2bf(v.y); o.z = f2bf(v.z); o.w = f2bf(v.w);
      *(ushort4*)(fbf + e) = o;
      uchar4 q;
      q.x = f2e4m3(v.x); q.y = f2e4m3(v.y); q.z = f2e4m3(v.z); q.w = f2e4m3(v.w);
      *(uchar4*)(f8 + e) = q;
    } else {
      int e2 = e - NF;
      float4 v = *(const float4*)(W + e2);
      ushort4 o;
      o.x = f2bf(v.x); o.y = f2bf(v.y); o.z = f2bf(v.z); o.w = f2bf(v.w);
      *(ushort4*)(wbf + e2) = o;
    }
  }
}

// K1: self row (bf16) + mean of 25 neighbor rows (fp8) -> hcat bf16 [NROW][1024]
__launch_bounds__(256, 3)
__global__ void gather_kernel(const unsigned short* __restrict__ fbf,
                              const unsigned char* __restrict__ f8,
                              const int* __restrict__ self_idx,
                              const int* __restrict__ neigh_idx,
                              unsigned short* __restrict__ hcat) {
  const int wid = threadIdx.x >> 6;
  const int lane = threadIdx.x & 63;
  const int n = blockIdx.x * 4 + wid;
  if (n >= NROW) return;
  const int col8 = lane * 8;   // 8 elems per lane covers 512 cols

  int si = __builtin_amdgcn_readfirstlane(self_idx[n]);
  uint4 sv = *(const uint4*)(fbf + (long)si * D + col8);
  *(uint4*)(hcat + (long)n * KDIM + col8) = sv;

  int idx[NSAMP];
#pragma unroll
  for (int s = 0; s < NSAMP; ++s)
    idx[s] = __builtin_amdgcn_readfirstlane(neigh_idx[n * NSAMP + s]);

  uint2 v[NSAMP];
#pragma unroll
  for (int s = 0; s < NSAMP; ++s)
    v[s] = *(const uint2*)(f8 + (long)idx[s] * D + col8);

  float acc[8];
#pragma unroll
  for (int j = 0; j < 8; ++j) acc[j] = 0.f;
#pragma unroll
  for (int s = 0; s < NSAMP; ++s) {
    acc_fp8x4(v[s].x, acc);
    acc_fp8x4(v[s].y, acc + 4);
  }
  unsigned short ob[8];
#pragma unroll
  for (int j = 0; j < 8; ++j) ob[j] = f2bf(acc[j] * (1.0f / NSAMP));
  *(uint4*)(hcat + (long)n * KDIM + D + col8) = *(uint4*)ob;
}

// K2: h = relu(hcat @ W^T + b) -> bf16, BM=128 x BN=128, BK=32, 4 waves (64x64 each).
// 3-deep LDS pipeline, counted vmcnt, XCD-swizzled grid, fused BN column stats.
// LDS per buf (ushort idx): A [sub0..3][row0..127][8]=4096, B same -> 8192/buf.
__launch_bounds__(256)
__global__ void gemm_kernel(const unsigned short* __restrict__ hcat,
                            const unsigned short* __restrict__ wbf,
                            const float* __restrict__ bias,
                            unsigned short* __restrict__ hbf,
                            float* __restrict__ csum,
                            float* __restrict__ csq) {
  __shared__ unsigned short lds[24576];   // 48 KB: 3 bufs x 8192 ushorts
  const int wg = blockIdx.x;
  const int xcd = wg & 7, pos = wg >> 3;
  const int mb = xcd + 8 * (pos >> 2);    // 4 nb-blocks of an mb share an XCD
  const int nb = pos & 3;
  if (mb >= MBLKS) return;

  const int tid = threadIdx.x;
  const int lane = tid & 63, wid = tid >> 6;
  const int wr = wid >> 1, wc = wid & 1;  // wave tile 64x64

  const int srow = tid & 127;
  const int sub0 = wid >> 1;              // = tid>>7
  int rowA = mb * BM + srow;
  if (rowA > NROW - 1) rowA = NROW - 1;   // clamp; excluded from stats/store
  const unsigned short* gA = hcat + (long)rowA * KDIM + sub0 * 8;
  const unsigned short* gB = wbf + (long)(nb * BN + srow) * KDIM + sub0 * 8;
  // wave-uniform LDS dest bases (ushort idx); HW adds lane*16B
  const int dRow = (wid & 1) * 512;       // row-block offset within sub-plane

  f32x4 acc[4][4];
#pragma unroll
  for (int i = 0; i < 4; ++i)
#pragma unroll
    for (int j = 0; j < 4; ++j) acc[i][j] = (f32x4){0.f, 0.f, 0.f, 0.f};

  const int koff = lane >> 4;   // 0..3
  const int r16 = lane & 15;

#define STAGE(buf, kt)                                                        \
  do {                                                                        \
    gload_lds16(gA + (kt),      &lds[(buf) * 8192 + (sub0)     * 1024 + dRow]); \
    gload_lds16(gA + (kt) + 16, &lds[(buf) * 8192 + (sub0 + 2) * 1024 + dRow]); \
    gload_lds16(gB + (kt),      &lds[(buf) * 8192 + 4096 + (sub0)     * 1024 + dRow]); \
    gload_lds16(gB + (kt) + 16, &lds[(buf) * 8192 + 4096 + (sub0 + 2) * 1024 + dRow]); \
  } while (0)

#define COMPUTE(BC)                                                           \
  do {                                                                        \
    bf16x8 af[4], bfr[4];                                                     \
    const int aOff = (BC) * 8192 + koff * 1024 + (wr * 64 + r16) * 8;         \
    const int bOff = (BC) * 8192 + 4096 + koff * 1024 + (wc * 64 + r16) * 8;  \
    _Pragma("unroll")                                                         \
    for (int mf = 0; mf < 4; ++mf) af[mf] = *(const bf16x8*)&lds[aOff + mf * 128]; \
    _Pragma("unroll")                                                         \
    for (int nf = 0; nf < 4; ++nf) bfr[nf] = *(const bf16x8*)&lds[bOff + nf * 128]; \
    _Pragma("unroll")                                                         \
    for (int mf = 0; mf < 4; ++mf)                                            \
      _Pragma("unroll")                                                       \
      for (int nf = 0; nf < 4; ++nf)                                          \
        acc[mf][nf] = __builtin_amdgcn_mfma_f32_16x16x32_bf16(                \
            af[mf], bfr[nf], acc[mf][nf], 0, 0, 0);                           \
  } while (0)

#define STEP(T, BC, BS)                                                       \
  do {                                                                        \
    if ((T) < NT) {                                                           \
      if ((T) + 2 < NT) {                                                     \
        STAGE(BS, ((T) + 2) * BK);                                            \
        asm volatile("s_waitcnt vmcnt(8)" ::: "memory");                      \
      } else if ((T) + 1 < NT) {                                              \
        asm volatile("s_waitcnt vmcnt(4)" ::: "memory");                      \
      } else {                                                                \
        asm volatile("s_waitcnt vmcnt(0)" ::: "memory");                      \
      }                                                                       \
      __builtin_amdgcn_s_barrier();                                           \
      COMPUTE(BC);                                                            \
      __builtin_amdgcn_s_barrier();                                           \
    }                                                                         \
  } while (0)

  STAGE(0, 0);
  STAGE(1, BK);
  for (int t = 0; t < NT; t += 3) {
    STEP(t,     0, 2);
    STEP(t + 1, 1, 0);
    STEP(t + 2, 2, 1);
  }
#undef STEP
#undef COMPUTE
#undef STAGE

  // epilogue: C/D layout col=lane&15, row=(lane>>4)*4+reg; fused BN stats
  const int rgrp = lane >> 4;
#pragma unroll
  for (int nf = 0; nf < 4; ++nf) {
    const int col = nb * BN + wc * 64 + nf * 16 + r16;
    const float bv = bias[col];
    float s = 0.f, q = 0.f;
#pragma unroll
    for (int mf = 0; mf < 4; ++mf) {
#pragma unroll
      for (int r = 0; r < 4; ++r) {
        const int m = mb * BM + wr * 64 + mf * 16 + rgrp * 4 + r;
        float v = acc[mf][nf][r] + bv;
        v = fmaxf(v, 0.f);
        if (m < NROW) {
          hbf[(long)m * D + col] = f2bf(v);
          s += v;
          q += v * v;
        }
      }
    }
    s += __shfl_xor(s, 16); s += __shfl_xor(s, 32);
    q += __shfl_xor(q, 16); q += __shfl_xor(q, 32);
    if (rgrp == 0) {
      atomicAdd(&csum[col], s);
      atomicAdd(&csq[col], q);
    }
  }
}

// K3: BN apply + row L2 normalize; wave-per-row, bf16 h input, hoisted params
__launch_bounds__(256)
__global__ void finalize_kernel(const unsigned short* __restrict__ hbf,
                                const float* __restrict__ csum,
                                const float* __restrict__ csq,
                                const float* __restrict__ gamma,
                                const float* __restrict__ beta,
                                float* __restrict__ out) {
  const int lane = threadIdx.x & 63, wid = threadIdx.x >> 6;
  const int c0 = lane * 8;

  float mu[8], g[8], be[8];
#pragma unroll
  for (int j = 0; j < 8; ++j) {
    const int c = c0 + j;
    const float m = csum[c] * (1.0f / NROW);
    float var = csq[c] * (1.0f / NROW) - m * m;
    var = fmaxf(var, 0.f);
    mu[j] = m;
    g[j]  = rsqrtf(var + 1e-5f) * gamma[c];
    be[j] = beta[c];
  }

  for (int r = blockIdx.x * 4 + wid; r < NROW; r += gridDim.x * 4) {
    uint4 hv = *(const uint4*)(hbf + (long)r * D + c0);
    const unsigned short* hu = (const unsigned short*)&hv;
    float y[8];
#pragma unroll
    for (int j = 0; j < 8; ++j) y[j] = (bf2f(hu[j]) - mu[j]) * g[j] + be[j];
    float ss = 0.f;
#pragma unroll
    for (int j = 0; j < 8; ++j) ss += y[j] * y[j];
#pragma unroll
    for (int off = 32; off > 0; off >>= 1) ss += __shfl_xor(ss, off);
    const float sc = 1.0f / (sqrtf(ss) + 1e-6f);
    float4 o0, o1;
    o0.x = y[0] * sc; o0.y = y[1] * sc; o0.z = y[2] * sc; o0.w = y[3] * sc;
    o1.x = y[4] * sc; o1.y = y[5] * sc; o1.z = y[6] * sc; o1.w = y[7] * sc;
    float* op = out + (long)r * D + c0;
    *(float4*)(op) = o0;
    *(float4*)(op + 4) = o1;
  }
}

extern "C" void kernel_launch(void* const* d_in, const int* in_sizes, int n_in,
                              void* d_out, int out_size, void* d_ws, size_t ws_size,
                              hipStream_t stream) {
  const float* feat  = (const float*)d_in[0];
  const float* W     = (const float*)d_in[1];
  const float* bias  = (const float*)d_in[2];
  const float* gamma = (const float*)d_in[3];
  const float* beta  = (const float*)d_in[4];
  const int* self_idx = (const int*)d_in[5];
  const int* neigh    = (const int*)d_in[6];
  float* out = (float*)d_out;

  char* ws = (char*)d_ws;
  unsigned short* fbf  = (unsigned short*)(ws);                    // 40,960,000 B
  unsigned short* wbf  = (unsigned short*)(ws + 40960000);         //  1,048,576 B
  unsigned char*  f8   = (unsigned char*)(ws + 42008576);          // 20,480,000 B
  unsigned short* hcat = (unsigned short*)(ws + 62488576);         // 40,960,000 B
  unsigned short* hbf  = (unsigned short*)(ws + 103448576);        // 20,480,000 B
  float* csum = (float*)(ws + 123928576);                          // 2048 B
  float* csq  = (float*)(ws + 123930624);                          // 2048 B

  hipMemsetAsync(csum, 0, 4096, stream);
  convert_kernel<<<2048, 256, 0, stream>>>(feat, W, fbf, wbf, f8);
  gather_kernel<<<(NROW + 3) / 4, 256, 0, stream>>>(fbf, f8, self_idx, neigh, hcat);
  gemm_kernel<<<8 * 20 * 4, 256, 0, stream>>>(hcat, wbf, bias, hbf, csum, csq);
  finalize_kernel<<<1250, 256, 0, stream>>>(hbf, csum, csq, gamma, beta, out);
}

// Round 9
// 266.719 us; speedup vs baseline: 1.2183x; 1.0334x over previous
//
#include <hip/hip_runtime.h>
#include <hip/hip_bf16.h>
#include <stdint.h>

#define N_TOTAL 40000
#define NROW    20000
#define D       512
#define NSAMP   25
#define KDIM    1024   // 2*D
#define BM      128
#define BN      128
#define BK      32
#define NT      (KDIM / BK)              // 32 K-steps
#define MBLKS   ((NROW + BM - 1) / BM)   // 157

typedef __bf16 bf16x8 __attribute__((ext_vector_type(8)));
typedef float  f32x4  __attribute__((ext_vector_type(4)));

__device__ inline float bf2f(unsigned short u) {
  union { uint32_t u; float f; } cv; cv.u = ((uint32_t)u) << 16; return cv.f;
}
__device__ inline unsigned short f2bf(float f) {
  union { float f; uint32_t u; } cv; cv.f = f;
  uint32_t u = cv.u;
  uint32_t r = (u + 0x7fffu + ((u >> 16) & 1u)) >> 16;  // RNE
  return (unsigned short)r;
}

// f32 -> e4m3fn (RNE, saturating). Inputs are N(0,1) — no overflow path hit.
__device__ inline unsigned char f2e4m3(float f) {
  union { float f; uint32_t u; } cv; cv.f = f;
  uint32_t u = cv.u;
  uint32_t s = (u >> 24) & 0x80;
  float a = fabsf(f);
  if (a < 0.001953125f) {
    uint32_t m = (uint32_t)(a * 512.0f + 0.5f);
    return (unsigned char)(s | m);
  }
  if (a > 448.0f) return (unsigned char)(s | 0x7E);
  int e = (int)((u >> 23) & 0xFF) - 127;
  if (e < -6) {
    uint32_t m = (uint32_t)(a * 512.0f + 0.5f);
    if (m >= 8) return (unsigned char)(s | 0x08);
    return (unsigned char)(s | m);
  }
  uint32_t mant = u & 0x7FFFFF;
  uint32_t keep = mant >> 20;
  uint32_t rest = mant & 0xFFFFF;
  uint32_t half = 0x80000;
  if (rest > half || (rest == half && (keep & 1))) {
    keep++;
    if (keep == 8) { keep = 0; e++; if (e > 8) return (unsigned char)(s | 0x7E); }
  }
  return (unsigned char)(s | ((uint32_t)(e + 7) << 3) | keep);
}

// e4m3fn -> f32 accumulate (denorms approximated as normals)
__device__ inline void acc_fp8x4(uint32_t w, float* acc) {
#pragma unroll
  for (int j = 0; j < 4; ++j) {
    uint32_t b = (w >> (8 * j)) & 0xFF;
    uint32_t t = b & 0x7F;
    uint32_t bits = (t << 20) + 0x3C000000;
    bits |= (b & 0x80) << 24;
    union { uint32_t u; float f; } cv; cv.u = bits;
    acc[j] += cv.f;
  }
}

__device__ inline void gload_lds16(const void* gsrc, void* ldst) {
  __builtin_amdgcn_global_load_lds(
      (const __attribute__((address_space(1))) uint32_t*)gsrc,
      (__attribute__((address_space(3))) uint32_t*)ldst,
      16, 0, 0);
}

// K0: features f32 -> e4m3 (f8); W f32 -> bf16 (wbf)
__global__ void convert_kernel(const float* __restrict__ feat,
                               const float* __restrict__ W,
                               unsigned short* __restrict__ wbf,
                               unsigned char* __restrict__ f8) {
  const int NF = N_TOTAL * D;      // 20,480,000
  const int NW = D * KDIM;         // 524,288
  const int total4 = (NF + NW) >> 2;
  for (int i = blockIdx.x * blockDim.x + threadIdx.x; i < total4;
       i += gridDim.x * blockDim.x) {
    int e = i << 2;
    if (e < NF) {
      float4 v = *(const float4*)(feat + e);
      uchar4 q;
      q.x = f2e4m3(v.x); q.y = f2e4m3(v.y); q.z = f2e4m3(v.z); q.w = f2e4m3(v.w);
      *(uchar4*)(f8 + e) = q;
    } else {
      int e2 = e - NF;
      float4 v = *(const float4*)(W + e2);
      ushort4 o;
      o.x = f2bf(v.x); o.y = f2bf(v.y); o.z = f2bf(v.z); o.w = f2bf(v.w);
      *(ushort4*)(wbf + e2) = o;
    }
  }
}

// K1: self row (f32, converted) + mean of 25 neighbor rows (fp8) -> hcat bf16
__launch_bounds__(256, 3)
__global__ void gather_kernel(const float* __restrict__ feat,
                              const unsigned char* __restrict__ f8,
                              const int* __restrict__ self_idx,
                              const int* __restrict__ neigh_idx,
                              unsigned short* __restrict__ hcat) {
  const int wid = threadIdx.x >> 6;
  const int lane = threadIdx.x & 63;
  const int n = blockIdx.x * 4 + wid;
  if (n >= NROW) return;
  const int col8 = lane * 8;

  int si = __builtin_amdgcn_readfirstlane(self_idx[n]);
  const float* srcf = feat + (long)si * D + col8;
  float4 a0 = *(const float4*)(srcf);
  float4 a1 = *(const float4*)(srcf + 4);
  unsigned short sb[8];
  sb[0] = f2bf(a0.x); sb[1] = f2bf(a0.y); sb[2] = f2bf(a0.z); sb[3] = f2bf(a0.w);
  sb[4] = f2bf(a1.x); sb[5] = f2bf(a1.y); sb[6] = f2bf(a1.z); sb[7] = f2bf(a1.w);
  *(uint4*)(hcat + (long)n * KDIM + col8) = *(uint4*)sb;

  int idx[NSAMP];
#pragma unroll
  for (int s = 0; s < NSAMP; ++s)
    idx[s] = __builtin_amdgcn_readfirstlane(neigh_idx[n * NSAMP + s]);

  uint2 v[NSAMP];
#pragma unroll
  for (int s = 0; s < NSAMP; ++s)
    v[s] = *(const uint2*)(f8 + (long)idx[s] * D + col8);

  float acc[8];
#pragma unroll
  for (int j = 0; j < 8; ++j) acc[j] = 0.f;
#pragma unroll
  for (int s = 0; s < NSAMP; ++s) {
    acc_fp8x4(v[s].x, acc);
    acc_fp8x4(v[s].y, acc + 4);
  }
  unsigned short ob[8];
#pragma unroll
  for (int j = 0; j < 8; ++j) ob[j] = f2bf(acc[j] * (1.0f / NSAMP));
  *(uint4*)(hcat + (long)n * KDIM + D + col8) = *(uint4*)ob;
}

// K2: h = relu(hcat @ W^T + b) -> bf16. BM=128 x BN=128, BK=32, 8 waves (32x64 each),
// 4-deep LDS pipeline (64 KB), counted vmcnt(6), XCD-swizzled grid, fused BN stats.
// LDS per buf (ushort idx): A [sub0..3][row0..127][8]=4096, B same -> 8192/buf.
__launch_bounds__(512, 4)
__global__ void gemm_kernel(const unsigned short* __restrict__ hcat,
                            const unsigned short* __restrict__ wbf,
                            const float* __restrict__ bias,
                            unsigned short* __restrict__ hbf,
                            float* __restrict__ csum,
                            float* __restrict__ csq) {
  __shared__ unsigned short lds[32768];   // 64 KB: 4 bufs x 8192 ushorts
  const int wg = blockIdx.x;
  const int xcd = wg & 7, pos = wg >> 3;
  const int mb = xcd + 8 * (pos >> 2);    // 4 nb-blocks of an mb share an XCD
  const int nb = pos & 3;
  if (mb >= MBLKS) return;

  const int tid = threadIdx.x;
  const int lane = tid & 63, wid = tid >> 6;   // wid 0..7
  const int wr = wid >> 1, wc = wid & 1;       // wave tile 32 rows x 64 cols

  const int srow = tid & 127;
  const int sub  = tid >> 7;                   // 0..3 (wave-uniform: wid>>1)
  int rowA = mb * BM + srow;
  if (rowA > NROW - 1) rowA = NROW - 1;        // clamp; excluded from stats/store
  const unsigned short* gA = hcat + (long)rowA * KDIM + sub * 8;
  const unsigned short* gB = wbf + (long)(nb * BN + srow) * KDIM + sub * 8;
  const int dA = sub * 1024 + (wid & 1) * 512; // wave-uniform dest base (ushort idx)

  f32x4 acc[2][4];
#pragma unroll
  for (int i = 0; i < 2; ++i)
#pragma unroll
    for (int j = 0; j < 4; ++j) acc[i][j] = (f32x4){0.f, 0.f, 0.f, 0.f};

  const int koff = lane >> 4;   // 0..3
  const int r16 = lane & 15;

#define STAGE(buf, kt)                                              \
  do {                                                              \
    gload_lds16(gA + (kt), &lds[(buf) * 8192 + dA]);                \
    gload_lds16(gB + (kt), &lds[(buf) * 8192 + 4096 + dA]);         \
  } while (0)

#define COMPUTE(BC)                                                           \
  do {                                                                        \
    bf16x8 af[2], bfr[4];                                                     \
    const int aOff = (BC) * 8192 + koff * 1024 + (wr * 32 + r16) * 8;         \
    const int bOff = (BC) * 8192 + 4096 + koff * 1024 + (wc * 64 + r16) * 8;  \
    _Pragma("unroll")                                                         \
    for (int mf = 0; mf < 2; ++mf) af[mf] = *(const bf16x8*)&lds[aOff + mf * 128]; \
    _Pragma("unroll")                                                         \
    for (int nf = 0; nf < 4; ++nf) bfr[nf] = *(const bf16x8*)&lds[bOff + nf * 128]; \
    _Pragma("unroll")                                                         \
    for (int nf = 0; nf < 4; ++nf)                                            \
      _Pragma("unroll")                                                       \
      for (int mf = 0; mf < 2; ++mf)                                          \
        acc[mf][nf] = __builtin_amdgcn_mfma_f32_16x16x32_bf16(                \
            af[mf], bfr[nf], acc[mf][nf], 0, 0, 0);                           \
  } while (0)

#define STEP(T, BC, BS)                                                       \
  do {                                                                        \
    if ((T) + 3 < NT) {                                                       \
      STAGE(BS, ((T) + 3) * BK);                                              \
      asm volatile("s_waitcnt vmcnt(6)" ::: "memory");                        \
    } else if ((T) + 2 < NT) {                                                \
      asm volatile("s_waitcnt vmcnt(4)" ::: "memory");                        \
    } else if ((T) + 1 < NT) {                                                \
      asm volatile("s_waitcnt vmcnt(2)" ::: "memory");                        \
    } else {                                                                  \
      asm volatile("s_waitcnt vmcnt(0)" ::: "memory");                        \
    }                                                                         \
    __builtin_amdgcn_s_barrier();                                             \
    COMPUTE(BC);                                                              \
    __builtin_amdgcn_s_barrier();                                             \
  } while (0)

  STAGE(0, 0);
  STAGE(1, BK);
  STAGE(2, 2 * BK);
  for (int t = 0; t < NT; t += 4) {   // NT=32, multiple of 4
    STEP(t,     0, 3);
    STEP(t + 1, 1, 0);
    STEP(t + 2, 2, 1);
    STEP(t + 3, 3, 2);
  }
#undef STEP
#undef COMPUTE
#undef STAGE

  // epilogue: C/D layout col=lane&15, row=(lane>>4)*4+reg; fused BN stats
  const int rgrp = lane >> 4;
#pragma unroll
  for (int nf = 0; nf < 4; ++nf) {
    const int col = nb * BN + wc * 64 + nf * 16 + r16;
    const float bv = bias[col];
    float s = 0.f, q = 0.f;
#pragma unroll
    for (int mf = 0; mf < 2; ++mf) {
#pragma unroll
      for (int r = 0; r < 4; ++r) {
        const int m = mb * BM + wr * 32 + mf * 16 + rgrp * 4 + r;
        float v = acc[mf][nf][r] + bv;
        v = fmaxf(v, 0.f);
        if (m < NROW) {
          hbf[(long)m * D + col] = f2bf(v);
          s += v;
          q += v * v;
        }
      }
    }
    s += __shfl_xor(s, 16); s += __shfl_xor(s, 32);
    q += __shfl_xor(q, 16); q += __shfl_xor(q, 32);
    if (rgrp == 0) {
      atomicAdd(&csum[col], s);
      atomicAdd(&csq[col], q);
    }
  }
}

// K3: BN apply + row L2 normalize; wave-per-row, bf16 h input, hoisted params
__launch_bounds__(256)
__global__ void finalize_kernel(const unsigned short* __restrict__ hbf,
                                const float* __restrict__ csum,
                                const float* __restrict__ csq,
                                const float* __restrict__ gamma,
                                const float* __restrict__ beta,
                                float* __restrict__ out) {
  const int lane = threadIdx.x & 63, wid = threadIdx.x >> 6;
  const int c0 = lane * 8;

  float mu[8], g[8], be[8];
#pragma unroll
  for (int j = 0; j < 8; ++j) {
    const int c = c0 + j;
    const float m = csum[c] * (1.0f / NROW);
    float var = csq[c] * (1.0f / NROW) - m * m;
    var = fmaxf(var, 0.f);
    mu[j] = m;
    g[j]  = rsqrtf(var + 1e-5f) * gamma[c];
    be[j] = beta[c];
  }

  for (int r = blockIdx.x * 4 + wid; r < NROW; r += gridDim.x * 4) {
    uint4 hv = *(const uint4*)(hbf + (long)r * D + c0);
    const unsigned short* hu = (const unsigned short*)&hv;
    float y[8];
#pragma unroll
    for (int j = 0; j < 8; ++j) y[j] = (bf2f(hu[j]) - mu[j]) * g[j] + be[j];
    float ss = 0.f;
#pragma unroll
    for (int j = 0; j < 8; ++j) ss += y[j] * y[j];
#pragma unroll
    for (int off = 32; off > 0; off >>= 1) ss += __shfl_xor(ss, off);
    const float sc = 1.0f / (sqrtf(ss) + 1e-6f);
    float4 o0, o1;
    o0.x = y[0] * sc; o0.y = y[1] * sc; o0.z = y[2] * sc; o0.w = y[3] * sc;
    o1.x = y[4] * sc; o1.y = y[5] * sc; o1.z = y[6] * sc; o1.w = y[7] * sc;
    float* op = out + (long)r * D + c0;
    *(float4*)(op) = o0;
    *(float4*)(op + 4) = o1;
  }
}

extern "C" void kernel_launch(void* const* d_in, const int* in_sizes, int n_in,
                              void* d_out, int out_size, void* d_ws, size_t ws_size,
                              hipStream_t stream) {
  const float* feat  = (const float*)d_in[0];
  const float* W     = (const float*)d_in[1];
  const float* bias  = (const float*)d_in[2];
  const float* gamma = (const float*)d_in[3];
  const float* beta  = (const float*)d_in[4];
  const int* self_idx = (const int*)d_in[5];
  const int* neigh    = (const int*)d_in[6];
  float* out = (float*)d_out;

  char* ws = (char*)d_ws;
  unsigned char*  f8   = (unsigned char*)(ws);                     // 20,480,000 B
  unsigned short* wbf  = (unsigned short*)(ws + 20480000);         //  1,048,576 B
  unsigned short* hcat = (unsigned short*)(ws + 21528576);         // 40,960,000 B
  unsigned short* hbf  = (unsigned short*)(ws + 62488576);         // 20,480,000 B
  float* csum = (float*)(ws + 82968576);                           // 2048 B
  float* csq  = (float*)(ws + 82970624);                           // 2048 B

  hipMemsetAsync(csum, 0, 4096, stream);
  convert_kernel<<<2048, 256, 0, stream>>>(feat, W, wbf, f8);
  gather_kernel<<<(NROW + 3) / 4, 256, 0, stream>>>(feat, f8, self_idx, neigh, hcat);
  gemm_kernel<<<8 * 20 * 4, 512, 0, stream>>>(hcat, wbf, bias, hbf, csum, csq);
  finalize_kernel<<<1250, 256, 0, stream>>>(hbf, csum, csq, gamma, beta, out);
}